// Round 11
// baseline (5029.123 us; speedup 1.0000x reference)
//
#include <hip/hip_runtime.h>

#define NNODES 50000
#define NEDGES 800000
#define HDIM 128
#define DOUT 64
#define NLAYERS 3
#define NEG_SLOPE 0.2f

#define NODE_OUT_ELEMS (NNODES * DOUT)             // 3,200,000
#define EDGE_OUT_ELEMS (NEDGES * 3)                // 2,400,000
#define GEMB_OFF (NODE_OUT_ELEMS + EDGE_OUT_ELEMS) // 5,600,000

__device__ __forceinline__ float bf2f(unsigned short u) {
    union { unsigned int i; float f; } v; v.i = ((unsigned int)u) << 16; return v.f;
}
__device__ __forceinline__ unsigned short f2bf(float f) {
    union { unsigned int i; float f; } v; v.f = f;
    unsigned int b = v.i;
    unsigned int r = (b + 0x7FFFu + ((b >> 16) & 1u)) >> 16;
    return (unsigned short)r;
}
__device__ __forceinline__ float leaky(float x) { return x > 0.f ? x : NEG_SLOPE * x; }

// Monotone float<->uint key for atomicMax-based segment_max.
__device__ __forceinline__ unsigned int fkey(float f) {
    unsigned int u = __float_as_uint(f);
    return (u & 0x80000000u) ? ~u : (u | 0x80000000u);
}
__device__ __forceinline__ float unfkey(unsigned int k) {
    unsigned int b = (k & 0x80000000u) ? (k & 0x7FFFFFFFu) : ~k;
    return __uint_as_float(b);   // k==0 -> NaN; fmaxf(NaN,x)=x, safe init
}

// Edge fetch: which=0 -> src, which=1 -> dst. iflag=1 -> int32, 0 -> int64.
__device__ __forceinline__ int eget(const int* e32, const int* iflag, int which, int e) {
    int idx = which * NEDGES + e;
    return (*iflag) ? e32[idx] : e32[2 * idx];
}

__global__ void zero_int_kernel(int* p, int n) {
    int i = blockIdx.x * 256 + threadIdx.x;
    if (i < n) p[i] = 0;
}
__global__ void zero_f32_kernel(float* p, int n) {
    int i = blockIdx.x * 256 + threadIdx.x;
    if (i < n) p[i] = 0.f;
}

// flag=1 -> float inputs are f32 (confirmed rounds 6-10).
__global__ void detect_f32_kernel(const unsigned short* xb, int* flag) {
    int hit = 0;
    for (int j = threadIdx.x; j < 4096; j += 256) {
        int e = (xb[j] >> 7) & 0xFF;
        if (e >= 0x90) hit = 1;
    }
    if (hit) atomicOr(flag, 1);
}
__global__ void detect_i64_kernel(const int* e32, int* flag) {
    int i = blockIdx.x * 256 + threadIdx.x;
    if (i < NEDGES) {
        if (e32[2 * i + 1] != 0) atomicOr(flag, 1);
    }
}

__global__ void cvt_kernel(const void* src, float* dst, int n, const int* f32flag) {
    int i = blockIdx.x * 256 + threadIdx.x;
    if (i < n)
        dst[i] = (*f32flag) ? ((const float*)src)[i]
                            : bf2f(((const unsigned short*)src)[i]);
}
__global__ void cvt_layerW_kernel(const void* gat_W, float* dst, int l,
                                  const int* f32flag) {
    int i = blockIdx.x * 256 + threadIdx.x;
    if (i < HDIM * HDIM) {
        size_t idx = (size_t)l * HDIM * HDIM + i;
        dst[i] = (*f32flag) ? ((const float*)gat_W)[idx]
                            : bf2f(((const unsigned short*)gat_W)[idx]);
    }
}

// C[M,N] = op(A[M,128] @ B[128,N] + bias). out_f32: C is float*, else bf16 u16*.
__global__ void gemm_any_kernel(const void* Av, int a_dyn, const void* Bv,
                                int b_pre_f32, const float* bias,
                                void* Cv, int out_f32,
                                int M, int N, int relu, const int* f32flag) {
    const int f32 = *f32flag;
    const int a_f32 = a_dyn ? f32 : 0;
    const int b_f32 = b_pre_f32 ? 1 : f32;
    __shared__ float sA[4 * 128];
    const int tid = threadIdx.x;
    const int rpb = 256 / N;
    const int row0 = blockIdx.x * rpb;

    for (int i = tid; i < rpb * 128; i += 256) {
        int r = i >> 7, k = i & 127;
        int gr = row0 + r;
        float v = 0.f;
        if (gr < M) {
            if (a_f32) v = ((const float*)Av)[(size_t)gr * 128 + k];
            else       v = bf2f(((const unsigned short*)Av)[(size_t)gr * 128 + k]);
        }
        sA[i] = v;
    }
    __syncthreads();

    const int r = tid / N, col = tid % N;
    const int row = row0 + r;
    if (row < M) {
        float acc = bias ? bias[col] : 0.f;
        const float* a = &sA[r * 128];
        if (b_f32) {
            const float* B = (const float*)Bv;
            for (int k = 0; k < 128; k++) acc += a[k] * B[(size_t)k * N + col];
        } else {
            const unsigned short* B = (const unsigned short*)Bv;
            for (int k = 0; k < 128; k++) acc += a[k] * bf2f(B[(size_t)k * N + col]);
        }
        if (relu) acc = fmaxf(acc, 0.f);
        if (out_f32) ((float*)Cv)[(size_t)row * N + col] = acc;
        else         ((unsigned short*)Cv)[(size_t)row * N + col] = f2bf(acc);
    }
}

__global__ void alpha_kernel(const unsigned short* xw,
                             const float* a_s, const float* a_d,
                             float* alpha_s, float* alpha_d) {
    int wave = threadIdx.x >> 6, lane = threadIdx.x & 63;
    int n = blockIdx.x * 4 + wave;
    if (n >= NNODES) return;
    float v0 = bf2f(xw[(size_t)n * HDIM + lane]);
    float v1 = bf2f(xw[(size_t)n * HDIM + 64 + lane]);
    float ds = v0 * a_s[lane] + v1 * a_s[64 + lane];
    float dd = v0 * a_d[lane] + v1 * a_d[64 + lane];
    for (int d = 32; d >= 1; d >>= 1) { ds += __shfl_xor(ds, d); dd += __shfl_xor(dd, d); }
    if (lane == 0) { alpha_s[n] = ds; alpha_d[n] = dd; }
}

// ---- reference-style segment ops (edge-parallel atomics) ----
__global__ void amax_edges_kernel(const int* e32, const int* iflag,
                                  const float* as_, const float* ad_,
                                  unsigned int* mkey) {
    int e = blockIdx.x * 256 + threadIdx.x;
    if (e < NEDGES) {
        int s = eget(e32, iflag, 0, e);
        int d = eget(e32, iflag, 1, e);
        float logit = leaky(as_[s] + ad_[d]);
        atomicMax(&mkey[d], fkey(logit));
    }
}
__global__ void m_final_kernel(const unsigned int* mkey,
                               const float* as_, const float* ad_,
                               float* mval) {
    int n = blockIdx.x * 256 + threadIdx.x;
    if (n < NNODES) {
        float me = unfkey(mkey[n]);              // NaN if no incoming edges
        float ls = leaky(as_[n] + ad_[n]);
        mval[n] = fmaxf(me, ls);                 // fmaxf(NaN,x)=x
    }
}
__global__ void accum_edges_kernel(const int* e32, const int* iflag,
                                   const float* as_, const float* ad_,
                                   const float* mval,
                                   const unsigned short* xw,
                                   float* denom, float* acc) {
    int wave = threadIdx.x >> 6, lane = threadIdx.x & 63;
    int e = blockIdx.x * 4 + wave;
    if (e >= NEDGES) return;
    int s = eget(e32, iflag, 0, e);
    int d = eget(e32, iflag, 1, e);
    float p = __expf(leaky(as_[s] + ad_[d]) - mval[d]);
    if (lane == 0) atomicAdd(&denom[d], p);
    atomicAdd(&acc[(size_t)d * HDIM + lane],      p * bf2f(xw[(size_t)s * HDIM + lane]));
    atomicAdd(&acc[(size_t)d * HDIM + 64 + lane], p * bf2f(xw[(size_t)s * HDIM + 64 + lane]));
}
__global__ void self_update_kernel(const float* as_, const float* ad_,
                                   const float* mval, const unsigned short* xw,
                                   const float* denom, const float* acc,
                                   const float* gat_b, unsigned short* h) {
    int wave = threadIdx.x >> 6, lane = threadIdx.x & 63;
    int n = blockIdx.x * 4 + wave;
    if (n >= NNODES) return;
    float p = __expf(leaky(as_[n] + ad_[n]) - mval[n]);
    float dn = denom[n] + p;
    float inv = 1.f / dn;
    size_t base = (size_t)n * HDIM;
    float a0 = (acc[base + lane]      + p * bf2f(xw[base + lane]))      * inv;
    float a1 = (acc[base + 64 + lane] + p * bf2f(xw[base + 64 + lane])) * inv;
    float h0 = bf2f(h[base + lane]), h1 = bf2f(h[base + 64 + lane]);
    float b0 = gat_b[lane],          b1 = gat_b[64 + lane];
    h[base + lane]      = f2bf(fmaxf(h0 + a0 + b0, 0.f));
    h[base + 64 + lane] = f2bf(fmaxf(h1 + a1 + b1, 0.f));
}

__global__ void edge_mlp_kernel(const unsigned short* h,
                                const int* e32, const int* iflag,
                                const float* We1, const float* be1,
                                const float* We2, const float* be2,
                                float* eout) {
    __shared__ float sEF[16][256];
    const int tid = threadIdx.x;
    const int jslot = tid & 15, elocal = tid >> 4;
    const int e0 = blockIdx.x * 16;

    for (int i = tid; i < 16 * 256; i += 256) {
        int el = i >> 8, k = i & 255;
        int e = e0 + el;
        int node = eget(e32, iflag, (k < 128) ? 0 : 1, e);
        sEF[el][k] = bf2f(h[(size_t)node * HDIM + (k & 127)]);
    }
    __syncthreads();

    float acc[8];
    for (int jj = 0; jj < 8; jj++) acc[jj] = be1[jslot * 8 + jj];

    for (int k = 0; k < 256; k++) {
        float ef = sEF[elocal][k];
        float4 w0 = *(const float4*)(We1 + (size_t)k * 128 + jslot * 8);
        float4 w1 = *(const float4*)(We1 + (size_t)k * 128 + jslot * 8 + 4);
        acc[0] += ef * w0.x; acc[1] += ef * w0.y;
        acc[2] += ef * w0.z; acc[3] += ef * w0.w;
        acc[4] += ef * w1.x; acc[5] += ef * w1.y;
        acc[6] += ef * w1.z; acc[7] += ef * w1.w;
    }

    float s0 = 0.f, s1 = 0.f, s2 = 0.f;
    for (int jj = 0; jj < 8; jj++) {
        int j = jslot * 8 + jj;
        float v = fmaxf(acc[jj], 0.f);
        s0 += v * We2[j * 3 + 0];
        s1 += v * We2[j * 3 + 1];
        s2 += v * We2[j * 3 + 2];
    }
    for (int d = 1; d < 16; d <<= 1) {
        s0 += __shfl_xor(s0, d); s1 += __shfl_xor(s1, d); s2 += __shfl_xor(s2, d);
    }
    if (jslot == 0) {
        int e = e0 + elocal;
        eout[(size_t)e * 3 + 0] = s0 + be2[0];
        eout[(size_t)e * 3 + 1] = s1 + be2[1];
        eout[(size_t)e * 3 + 2] = s2 + be2[2];
    }
}

__global__ void gsum_kernel(const unsigned short* h, float* gsum) {
    int f = threadIdx.x;
    float local = 0.f;
    int n0 = blockIdx.x * 200;
    for (int j = 0; j < 200; j++) local += bf2f(h[(size_t)(n0 + j) * HDIM + f]);
    atomicAdd(&gsum[f], local);
}
__global__ void gout_kernel(const float* gsum, float* out) {
    int f = threadIdx.x;
    out[GEMB_OFF + f] = gsum[f] * (1.f / (float)NNODES);
}

extern "C" __attribute__((visibility("default")))
void kernel_launch(void* const* d_in, const int* in_sizes, int n_in,
                   void* d_out, int out_size, void* d_ws, size_t ws_size,
                   hipStream_t stream) {
    const void* x      = d_in[0];
    const int*  eidx   = (const int*)d_in[1];
    const void* W_emb  = d_in[2];
    const void* b_emb  = d_in[3];
    const void* gat_W  = d_in[4];
    const void* gat_as = d_in[5];
    const void* gat_ad = d_in[6];
    const void* gat_b  = d_in[7];
    const void* Wn1    = d_in[8];
    const void* bn1    = d_in[9];
    const void* Wn2    = d_in[10];
    const void* bn2    = d_in[11];
    const void* We1    = d_in[12];
    const void* be1    = d_in[13];
    const void* We2    = d_in[14];
    const void* be2    = d_in[15];
    float* out = (float*)d_out;   // OUTPUT IS FLOAT32 (reference output dtype)

    char* ws = (char*)d_ws;
    unsigned short* h     = (unsigned short*)(ws);               // 12.8 MB
    unsigned short* xw    = (unsigned short*)(ws + 12800000);    // 12.8 MB
    float*        accbuf  = (float*)(ws + 25600000);             // 25.6 MB f32 [N,128]
    float*        alpha_s = (float*)(ws + 51200000);             // 200 KB
    float*        alpha_d = (float*)(ws + 51400000);             // 200 KB
    float*        mval    = (float*)(ws + 51600000);             // 200 KB
    unsigned int* mkey    = (unsigned int*)(ws + 51800000);      // 200 KB
    float*        denom   = (float*)(ws + 52000000);             // 200 KB
    float*        gsum    = (float*)(ws + 52200000);             // 512 B
    int*          iflag   = (int*)(ws + 52200512);               // 4 B
    int*          fflag   = (int*)(ws + 52200516);               // 4 B
    float*        We1c    = (float*)(ws + 52201024);             // 128 KB
    float*        We2c    = (float*)(ws + 52332096);
    float*        asc     = (float*)(ws + 52333632);
    float*        adc     = (float*)(ws + 52335168);
    float*        gbc     = (float*)(ws + 52336704);
    float*        bembc   = (float*)(ws + 52338240);
    float*        bn1c    = (float*)(ws + 52338752);
    float*        bn2c    = (float*)(ws + 52339264);
    float*        be1c    = (float*)(ws + 52339520);
    float*        be2c    = (float*)(ws + 52340032);
    float*        Wlc     = (float*)(ws + 52341056);             // 64 KB -> top ~52.4 MB

    const int node_blks = (NNODES + 255) / 256;    // 196
    const int edge_blks = (NEDGES + 255) / 256;    // 3125
    const int accz_blks = (NNODES * HDIM + 255) / 256;  // 25000

    zero_int_kernel<<<1, 256, 0, stream>>>(iflag, 2);   // iflag + fflag
    zero_f32_kernel<<<1, 256, 0, stream>>>(gsum, HDIM);

    detect_f32_kernel<<<1, 256, 0, stream>>>((const unsigned short*)x, fflag);
    detect_i64_kernel<<<edge_blks, 256, 0, stream>>>(eidx, iflag);

    cvt_kernel<<<128, 256, 0, stream>>>(We1, We1c, 256 * 128, fflag);
    cvt_kernel<<<2, 256, 0, stream>>>(We2, We2c, 128 * 3, fflag);
    cvt_kernel<<<2, 256, 0, stream>>>(gat_as, asc, 3 * 128, fflag);
    cvt_kernel<<<2, 256, 0, stream>>>(gat_ad, adc, 3 * 128, fflag);
    cvt_kernel<<<2, 256, 0, stream>>>(gat_b, gbc, 3 * 128, fflag);
    cvt_kernel<<<1, 256, 0, stream>>>(b_emb, bembc, 128, fflag);
    cvt_kernel<<<1, 256, 0, stream>>>(bn1, bn1c, 128, fflag);
    cvt_kernel<<<1, 256, 0, stream>>>(bn2, bn2c, 64, fflag);
    cvt_kernel<<<1, 256, 0, stream>>>(be1, be1c, 128, fflag);
    cvt_kernel<<<1, 256, 0, stream>>>(be2, be2c, 3, fflag);

    // h = relu(x @ W_emb + b_emb)   (bf16 intermediate)
    gemm_any_kernel<<<(NNODES + 1) / 2, 256, 0, stream>>>(
        x, 1, W_emb, 0, bembc, h, 0, NNODES, 128, 1, fflag);

    for (int l = 0; l < NLAYERS; l++) {
        cvt_layerW_kernel<<<64, 256, 0, stream>>>(gat_W, Wlc, l, fflag);
        gemm_any_kernel<<<(NNODES + 1) / 2, 256, 0, stream>>>(
            h, 0, Wlc, 1, (const float*)0, xw, 0, NNODES, 128, 0, fflag);
        alpha_kernel<<<(NNODES + 3) / 4, 256, 0, stream>>>(
            xw, asc + l * HDIM, adc + l * HDIM, alpha_s, alpha_d);

        zero_int_kernel<<<node_blks, 256, 0, stream>>>((int*)mkey, NNODES);
        zero_f32_kernel<<<node_blks, 256, 0, stream>>>(denom, NNODES);
        zero_f32_kernel<<<accz_blks, 256, 0, stream>>>(accbuf, NNODES * HDIM);
        amax_edges_kernel<<<edge_blks, 256, 0, stream>>>(eidx, iflag, alpha_s, alpha_d, mkey);
        m_final_kernel<<<node_blks, 256, 0, stream>>>(mkey, alpha_s, alpha_d, mval);
        accum_edges_kernel<<<(NEDGES + 3) / 4, 256, 0, stream>>>(
            eidx, iflag, alpha_s, alpha_d, mval, xw, denom, accbuf);
        self_update_kernel<<<(NNODES + 3) / 4, 256, 0, stream>>>(
            alpha_s, alpha_d, mval, xw, denom, accbuf, gbc + l * HDIM, h);
    }

    // node MLP: hidden (bf16 in xw), then node_pred -> f32 out
    gemm_any_kernel<<<(NNODES + 1) / 2, 256, 0, stream>>>(
        h, 0, Wn1, 0, bn1c, xw, 0, NNODES, 128, 1, fflag);
    gemm_any_kernel<<<(NNODES + 3) / 4, 256, 0, stream>>>(
        xw, 0, Wn2, 0, bn2c, out, 1, NNODES, 64, 0, fflag);

    // edge MLP -> f32 out
    edge_mlp_kernel<<<NEDGES / 16, 256, 0, stream>>>(
        h, eidx, iflag, We1c, be1c, We2c, be2c, out + NODE_OUT_ELEMS);

    // graph embedding -> f32 out
    gsum_kernel<<<NNODES / 200, 128, 0, stream>>>(h, gsum);
    gout_kernel<<<1, 128, 0, stream>>>(gsum, out);
}

// Round 12
// 2425.314 us; speedup vs baseline: 2.0736x; 2.0736x over previous
//
#include <hip/hip_runtime.h>

#define NNODES 50000
#define NEDGES 800000
#define HDIM 128
#define DOUT 64
#define NLAYERS 3
#define NEG_SLOPE 0.2f

#define NODE_OUT_ELEMS (NNODES * DOUT)             // 3,200,000
#define EDGE_OUT_ELEMS (NEDGES * 3)                // 2,400,000
#define GEMB_OFF (NODE_OUT_ELEMS + EDGE_OUT_ELEMS) // 5,600,000

typedef __attribute__((ext_vector_type(8))) short short8;
typedef __attribute__((ext_vector_type(4))) float f32x4;

__device__ __forceinline__ float bf2f(unsigned short u) {
    union { unsigned int i; float f; } v; v.i = ((unsigned int)u) << 16; return v.f;
}
__device__ __forceinline__ unsigned short f2bf(float f) {
    union { unsigned int i; float f; } v; v.f = f;
    unsigned int b = v.i;
    unsigned int r = (b + 0x7FFFu + ((b >> 16) & 1u)) >> 16;
    return (unsigned short)r;
}
__device__ __forceinline__ float leaky(float x) { return x > 0.f ? x : NEG_SLOPE * x; }

// Monotone float<->uint key for atomicMax-based segment_max.
__device__ __forceinline__ unsigned int fkey(float f) {
    unsigned int u = __float_as_uint(f);
    return (u & 0x80000000u) ? ~u : (u | 0x80000000u);
}
__device__ __forceinline__ float unfkey(unsigned int k) {
    unsigned int b = (k & 0x80000000u) ? (k & 0x7FFFFFFFu) : ~k;
    return __uint_as_float(b);   // k==0 -> NaN; fmaxf(NaN,x)=x, safe init
}

// Edge fetch: which=0 -> src, which=1 -> dst. iflag=1 -> int32, 0 -> int64.
__device__ __forceinline__ int eget(const int* e32, const int* iflag, int which, int e) {
    int idx = which * NEDGES + e;
    return (*iflag) ? e32[idx] : e32[2 * idx];
}

__global__ void zero_int_kernel(int* p, int n) {
    int i = blockIdx.x * 256 + threadIdx.x;
    if (i < n) p[i] = 0;
}
__global__ void zero_f32_kernel(float* p, int n) {
    int i = blockIdx.x * 256 + threadIdx.x;
    if (i < n) p[i] = 0.f;
}

__global__ void detect_f32_kernel(const unsigned short* xb, int* flag) {
    int hit = 0;
    for (int j = threadIdx.x; j < 4096; j += 256) {
        int e = (xb[j] >> 7) & 0xFF;
        if (e >= 0x90) hit = 1;
    }
    if (hit) atomicOr(flag, 1);
}
__global__ void detect_i64_kernel(const int* e32, int* flag) {
    int i = blockIdx.x * 256 + threadIdx.x;
    if (i < NEDGES) {
        if (e32[2 * i + 1] != 0) atomicOr(flag, 1);
    }
}

__global__ void cvt_kernel(const void* src, float* dst, int n, const int* f32flag) {
    int i = blockIdx.x * 256 + threadIdx.x;
    if (i < n)
        dst[i] = (*f32flag) ? ((const float*)src)[i]
                            : bf2f(((const unsigned short*)src)[i]);
}
__global__ void cvt_layerW_kernel(const void* gat_W, float* dst, int l,
                                  const int* f32flag) {
    int i = blockIdx.x * 256 + threadIdx.x;
    if (i < HDIM * HDIM) {
        size_t idx = (size_t)l * HDIM * HDIM + i;
        dst[i] = (*f32flag) ? ((const float*)gat_W)[idx]
                            : bf2f(((const unsigned short*)gat_W)[idx]);
    }
}

// C[M,N] = op(A[M,128] @ B[128,N] + bias). out_f32: C is float*, else bf16 u16*.
__global__ void gemm_any_kernel(const void* Av, int a_dyn, const void* Bv,
                                int b_pre_f32, const float* bias,
                                void* Cv, int out_f32,
                                int M, int N, int relu, const int* f32flag) {
    const int f32 = *f32flag;
    const int a_f32 = a_dyn ? f32 : 0;
    const int b_f32 = b_pre_f32 ? 1 : f32;
    __shared__ float sA[4 * 128];
    const int tid = threadIdx.x;
    const int rpb = 256 / N;
    const int row0 = blockIdx.x * rpb;

    for (int i = tid; i < rpb * 128; i += 256) {
        int r = i >> 7, k = i & 127;
        int gr = row0 + r;
        float v = 0.f;
        if (gr < M) {
            if (a_f32) v = ((const float*)Av)[(size_t)gr * 128 + k];
            else       v = bf2f(((const unsigned short*)Av)[(size_t)gr * 128 + k]);
        }
        sA[i] = v;
    }
    __syncthreads();

    const int r = tid / N, col = tid % N;
    const int row = row0 + r;
    if (row < M) {
        float acc = bias ? bias[col] : 0.f;
        const float* a = &sA[r * 128];
        if (b_f32) {
            const float* B = (const float*)Bv;
            for (int k = 0; k < 128; k++) acc += a[k] * B[(size_t)k * N + col];
        } else {
            const unsigned short* B = (const unsigned short*)Bv;
            for (int k = 0; k < 128; k++) acc += a[k] * bf2f(B[(size_t)k * N + col]);
        }
        if (relu) acc = fmaxf(acc, 0.f);
        if (out_f32) ((float*)Cv)[(size_t)row * N + col] = acc;
        else         ((unsigned short*)Cv)[(size_t)row * N + col] = f2bf(acc);
    }
}

__global__ void alpha_kernel(const unsigned short* xw,
                             const float* a_s, const float* a_d,
                             float* alpha_s, float* alpha_d) {
    int wave = threadIdx.x >> 6, lane = threadIdx.x & 63;
    int n = blockIdx.x * 4 + wave;
    if (n >= NNODES) return;
    float v0 = bf2f(xw[(size_t)n * HDIM + lane]);
    float v1 = bf2f(xw[(size_t)n * HDIM + 64 + lane]);
    float ds = v0 * a_s[lane] + v1 * a_s[64 + lane];
    float dd = v0 * a_d[lane] + v1 * a_d[64 + lane];
    for (int d = 32; d >= 1; d >>= 1) { ds += __shfl_xor(ds, d); dd += __shfl_xor(dd, d); }
    if (lane == 0) { alpha_s[n] = ds; alpha_d[n] = dd; }
}

// ---- reference-style segment ops (edge-parallel atomics) ----
__global__ void amax_edges_kernel(const int* e32, const int* iflag,
                                  const float* as_, const float* ad_,
                                  unsigned int* mkey) {
    int e = blockIdx.x * 256 + threadIdx.x;
    if (e < NEDGES) {
        int s = eget(e32, iflag, 0, e);
        int d = eget(e32, iflag, 1, e);
        float logit = leaky(as_[s] + ad_[d]);
        atomicMax(&mkey[d], fkey(logit));
    }
}
__global__ void m_final_kernel(const unsigned int* mkey,
                               const float* as_, const float* ad_,
                               float* mval) {
    int n = blockIdx.x * 256 + threadIdx.x;
    if (n < NNODES) {
        float me = unfkey(mkey[n]);
        float ls = leaky(as_[n] + ad_[n]);
        mval[n] = fmaxf(me, ls);
    }
}
__global__ void accum_edges_kernel(const int* e32, const int* iflag,
                                   const float* as_, const float* ad_,
                                   const float* mval,
                                   const unsigned short* xw,
                                   float* denom, float* acc) {
    int wave = threadIdx.x >> 6, lane = threadIdx.x & 63;
    int e = blockIdx.x * 4 + wave;
    if (e >= NEDGES) return;
    int s = eget(e32, iflag, 0, e);
    int d = eget(e32, iflag, 1, e);
    float p = __expf(leaky(as_[s] + ad_[d]) - mval[d]);
    if (lane == 0) atomicAdd(&denom[d], p);
    atomicAdd(&acc[(size_t)d * HDIM + lane],      p * bf2f(xw[(size_t)s * HDIM + lane]));
    atomicAdd(&acc[(size_t)d * HDIM + 64 + lane], p * bf2f(xw[(size_t)s * HDIM + 64 + lane]));
}
__global__ void self_update_kernel(const float* as_, const float* ad_,
                                   const float* mval, const unsigned short* xw,
                                   const float* denom, const float* acc,
                                   const float* gat_b, unsigned short* h) {
    int wave = threadIdx.x >> 6, lane = threadIdx.x & 63;
    int n = blockIdx.x * 4 + wave;
    if (n >= NNODES) return;
    float p = __expf(leaky(as_[n] + ad_[n]) - mval[n]);
    float dn = denom[n] + p;
    float inv = 1.f / dn;
    size_t base = (size_t)n * HDIM;
    float a0 = (acc[base + lane]      + p * bf2f(xw[base + lane]))      * inv;
    float a1 = (acc[base + 64 + lane] + p * bf2f(xw[base + 64 + lane])) * inv;
    float h0 = bf2f(h[base + lane]), h1 = bf2f(h[base + 64 + lane]);
    float b0 = gat_b[lane],          b1 = gat_b[64 + lane];
    h[base + lane]      = f2bf(fmaxf(h0 + a0 + b0, 0.f));
    h[base + 64 + lane] = f2bf(fmaxf(h1 + a1 + b1, 0.f));
}

// ---------------------------------------------------------------------------
// MFMA Edge MLP: out[e,0:3] = relu([h[src]||h[dst]] @ We1 + be1) @ We2 + be2
// 64-edge tiles, 4 waves; each wave: 64 edges x 32 hidden cols, K=256.
// We1 B-fragments in registers (bf16, converted from f32 scratch once).
// Second GEMM (128->3) fused: per-lane partials + 16-lane shuffle reduce.
// LDS: 64*264*2 + 64*4*3*4 = 36.9 KB.
// ---------------------------------------------------------------------------
__global__ __launch_bounds__(256) void edge_mlp_mfma_kernel(
    const unsigned short* __restrict__ h,
    const int* __restrict__ e32, const int* __restrict__ iflag,
    const float* __restrict__ We1, const float* __restrict__ be1,
    const float* __restrict__ We2, const float* __restrict__ be2,
    float* __restrict__ eout)
{
    constexpr int KP = 256 + 8;                   // padded pitch (elems)
    __shared__ unsigned short lEF[64 * KP];       // 33,792 B
    __shared__ float part[64][4][3];              //  3,072 B

    const int tid  = threadIdx.x;
    const int wave = tid >> 6, lane = tid & 63;
    const int quad = lane >> 4, l15 = lane & 15;
    const int ncol0 = wave * 32;

    // Preload We1 B-fragments (bf16): bw[kk][nt][j] = We1[kk*32+quad*8+j][ncol0+nt*16+l15]
    short8 bw[8][2];
    for (int kk = 0; kk < 8; kk++) {
        for (int nt = 0; nt < 2; nt++) {
            short8 t;
            int n = ncol0 + nt * 16 + l15;
            #pragma unroll
            for (int j = 0; j < 8; j++)
                t[j] = (short)f2bf(We1[(size_t)(kk * 32 + quad * 8 + j) * HDIM + n]);
            bw[kk][nt] = t;
        }
    }

    // epilogue constants for this wave's cols
    float w2[2][3], b1v[2];
    for (int nt = 0; nt < 2; nt++) {
        int n = ncol0 + nt * 16 + l15;
        b1v[nt] = be1[n];
        for (int c = 0; c < 3; c++) w2[nt][c] = We2[n * 3 + c];
    }
    float be2v[3];
    for (int c = 0; c < 3; c++) be2v[c] = be2[c];

    f32x4 vzero; vzero[0] = 0.f; vzero[1] = 0.f; vzero[2] = 0.f; vzero[3] = 0.f;

    const int ntiles = NEDGES / 64;               // 12500
    for (int tile = blockIdx.x; tile < ntiles; tile += gridDim.x) {
        const int e0 = tile * 64;
        // stage EF: 64 rows x 32 chunks(16B); cols 0..127 h[src], 128..255 h[dst]
        for (int c = tid; c < 64 * 32; c += 256) {
            int r = c >> 5, ck = c & 31;
            int e = e0 + r;
            int node = eget(e32, iflag, (ck < 16) ? 0 : 1, e);
            uint4 v = *(const uint4*)(h + (size_t)node * HDIM + (ck & 15) * 8);
            *(uint4*)(&lEF[r * KP + ck * 8]) = v;
        }
        __syncthreads();

        f32x4 acc[4][2];
        for (int mt = 0; mt < 4; mt++)
            for (int nt = 0; nt < 2; nt++)
                acc[mt][nt] = vzero;

        #pragma unroll
        for (int kk = 0; kk < 8; kk++) {
            short8 a[4];
            #pragma unroll
            for (int mt = 0; mt < 4; mt++)
                a[mt] = *(const short8*)(&lEF[(mt * 16 + l15) * KP + kk * 32 + quad * 8]);
            #pragma unroll
            for (int mt = 0; mt < 4; mt++)
                #pragma unroll
                for (int nt = 0; nt < 2; nt++)
                    acc[mt][nt] = __builtin_amdgcn_mfma_f32_16x16x32_bf16(a[mt], bw[kk][nt], acc[mt][nt], 0, 0, 0);
        }

        // fused second GEMM: hidden -> 3
        #pragma unroll
        for (int mt = 0; mt < 4; mt++) {
            #pragma unroll
            for (int q = 0; q < 4; q++) {
                int r = mt * 16 + quad * 4 + q;
                float s0 = 0.f, s1 = 0.f, s2 = 0.f;
                #pragma unroll
                for (int nt = 0; nt < 2; nt++) {
                    float v = fmaxf(acc[mt][nt][q] + b1v[nt], 0.f);
                    s0 += v * w2[nt][0]; s1 += v * w2[nt][1]; s2 += v * w2[nt][2];
                }
                #pragma unroll
                for (int d = 1; d < 16; d <<= 1) {
                    s0 += __shfl_xor(s0, d); s1 += __shfl_xor(s1, d); s2 += __shfl_xor(s2, d);
                }
                if (l15 == 0) { part[r][wave][0] = s0; part[r][wave][1] = s1; part[r][wave][2] = s2; }
            }
        }
        __syncthreads();

        for (int idx = tid; idx < 64 * 3; idx += 256) {
            int e = idx / 3, c = idx % 3;
            eout[(size_t)(e0 + e) * 3 + c] =
                part[e][0][c] + part[e][1][c] + part[e][2][c] + part[e][3][c] + be2v[c];
        }
        __syncthreads();
    }
}

__global__ void gsum_kernel(const unsigned short* h, float* gsum) {
    int f = threadIdx.x;
    float local = 0.f;
    int n0 = blockIdx.x * 200;
    for (int j = 0; j < 200; j++) local += bf2f(h[(size_t)(n0 + j) * HDIM + f]);
    atomicAdd(&gsum[f], local);
}
__global__ void gout_kernel(const float* gsum, float* out) {
    int f = threadIdx.x;
    out[GEMB_OFF + f] = gsum[f] * (1.f / (float)NNODES);
}

extern "C" __attribute__((visibility("default")))
void kernel_launch(void* const* d_in, const int* in_sizes, int n_in,
                   void* d_out, int out_size, void* d_ws, size_t ws_size,
                   hipStream_t stream) {
    const void* x      = d_in[0];
    const int*  eidx   = (const int*)d_in[1];
    const void* W_emb  = d_in[2];
    const void* b_emb  = d_in[3];
    const void* gat_W  = d_in[4];
    const void* gat_as = d_in[5];
    const void* gat_ad = d_in[6];
    const void* gat_b  = d_in[7];
    const void* Wn1    = d_in[8];
    const void* bn1    = d_in[9];
    const void* Wn2    = d_in[10];
    const void* bn2    = d_in[11];
    const void* We1    = d_in[12];
    const void* be1    = d_in[13];
    const void* We2    = d_in[14];
    const void* be2    = d_in[15];
    float* out = (float*)d_out;   // output dtype: float32 (confirmed round 11)

    char* ws = (char*)d_ws;
    unsigned short* h     = (unsigned short*)(ws);               // 12.8 MB
    unsigned short* xw    = (unsigned short*)(ws + 12800000);    // 12.8 MB
    float*        accbuf  = (float*)(ws + 25600000);             // 25.6 MB
    float*        alpha_s = (float*)(ws + 51200000);
    float*        alpha_d = (float*)(ws + 51400000);
    float*        mval    = (float*)(ws + 51600000);
    unsigned int* mkey    = (unsigned int*)(ws + 51800000);
    float*        denom   = (float*)(ws + 52000000);
    float*        gsum    = (float*)(ws + 52200000);
    int*          iflag   = (int*)(ws + 52200512);
    int*          fflag   = (int*)(ws + 52200516);
    float*        We1c    = (float*)(ws + 52201024);             // 128 KB
    float*        We2c    = (float*)(ws + 52332096);
    float*        asc     = (float*)(ws + 52333632);
    float*        adc     = (float*)(ws + 52335168);
    float*        gbc     = (float*)(ws + 52336704);
    float*        bembc   = (float*)(ws + 52338240);
    float*        bn1c    = (float*)(ws + 52338752);
    float*        bn2c    = (float*)(ws + 52339264);
    float*        be1c    = (float*)(ws + 52339520);
    float*        be2c    = (float*)(ws + 52340032);
    float*        Wlc     = (float*)(ws + 52341056);             // 64 KB

    const int node_blks = (NNODES + 255) / 256;
    const int edge_blks = (NEDGES + 255) / 256;
    const int accz_blks = (NNODES * HDIM + 255) / 256;

    zero_int_kernel<<<1, 256, 0, stream>>>(iflag, 2);
    zero_f32_kernel<<<1, 256, 0, stream>>>(gsum, HDIM);

    detect_f32_kernel<<<1, 256, 0, stream>>>((const unsigned short*)x, fflag);
    detect_i64_kernel<<<edge_blks, 256, 0, stream>>>(eidx, iflag);

    cvt_kernel<<<128, 256, 0, stream>>>(We1, We1c, 256 * 128, fflag);
    cvt_kernel<<<2, 256, 0, stream>>>(We2, We2c, 128 * 3, fflag);
    cvt_kernel<<<2, 256, 0, stream>>>(gat_as, asc, 3 * 128, fflag);
    cvt_kernel<<<2, 256, 0, stream>>>(gat_ad, adc, 3 * 128, fflag);
    cvt_kernel<<<2, 256, 0, stream>>>(gat_b, gbc, 3 * 128, fflag);
    cvt_kernel<<<1, 256, 0, stream>>>(b_emb, bembc, 128, fflag);
    cvt_kernel<<<1, 256, 0, stream>>>(bn1, bn1c, 128, fflag);
    cvt_kernel<<<1, 256, 0, stream>>>(bn2, bn2c, 64, fflag);
    cvt_kernel<<<1, 256, 0, stream>>>(be1, be1c, 128, fflag);
    cvt_kernel<<<1, 256, 0, stream>>>(be2, be2c, 3, fflag);

    // h = relu(x @ W_emb + b_emb)   (bf16 intermediate)
    gemm_any_kernel<<<(NNODES + 1) / 2, 256, 0, stream>>>(
        x, 1, W_emb, 0, bembc, h, 0, NNODES, 128, 1, fflag);

    for (int l = 0; l < NLAYERS; l++) {
        cvt_layerW_kernel<<<64, 256, 0, stream>>>(gat_W, Wlc, l, fflag);
        gemm_any_kernel<<<(NNODES + 1) / 2, 256, 0, stream>>>(
            h, 0, Wlc, 1, (const float*)0, xw, 0, NNODES, 128, 0, fflag);
        alpha_kernel<<<(NNODES + 3) / 4, 256, 0, stream>>>(
            xw, asc + l * HDIM, adc + l * HDIM, alpha_s, alpha_d);

        zero_int_kernel<<<node_blks, 256, 0, stream>>>((int*)mkey, NNODES);
        zero_f32_kernel<<<node_blks, 256, 0, stream>>>(denom, NNODES);
        zero_f32_kernel<<<accz_blks, 256, 0, stream>>>(accbuf, NNODES * HDIM);
        amax_edges_kernel<<<edge_blks, 256, 0, stream>>>(eidx, iflag, alpha_s, alpha_d, mkey);
        m_final_kernel<<<node_blks, 256, 0, stream>>>(mkey, alpha_s, alpha_d, mval);
        accum_edges_kernel<<<(NEDGES + 3) / 4, 256, 0, stream>>>(
            eidx, iflag, alpha_s, alpha_d, mval, xw, denom, accbuf);
        self_update_kernel<<<(NNODES + 3) / 4, 256, 0, stream>>>(
            alpha_s, alpha_d, mval, xw, denom, accbuf, gbc + l * HDIM, h);
    }

    // node MLP
    gemm_any_kernel<<<(NNODES + 1) / 2, 256, 0, stream>>>(
        h, 0, Wn1, 0, bn1c, xw, 0, NNODES, 128, 1, fflag);
    gemm_any_kernel<<<(NNODES + 3) / 4, 256, 0, stream>>>(
        xw, 0, Wn2, 0, bn2c, out, 1, NNODES, 64, 0, fflag);

    // edge MLP (MFMA)
    edge_mlp_mfma_kernel<<<12500, 256, 0, stream>>>(
        h, eidx, iflag, We1c, be1c, We2c, be2c, out + NODE_OUT_ELEMS);

    // graph embedding
    gsum_kernel<<<NNODES / 200, 128, 0, stream>>>(h, gsum);
    gout_kernel<<<1, 128, 0, stream>>>(gsum, out);
}

// Round 13
// 1500.058 us; speedup vs baseline: 3.3526x; 1.6168x over previous
//
#include <hip/hip_runtime.h>

#define NNODES 50000
#define NEDGES 800000
#define HDIM 128
#define DOUT 64
#define NLAYERS 3
#define NEG_SLOPE 0.2f

#define NODE_OUT_ELEMS (NNODES * DOUT)             // 3,200,000
#define EDGE_OUT_ELEMS (NEDGES * 3)                // 2,400,000
#define GEMB_OFF (NODE_OUT_ELEMS + EDGE_OUT_ELEMS) // 5,600,000

typedef __attribute__((ext_vector_type(8))) short short8;
typedef __attribute__((ext_vector_type(4))) float f32x4;

__device__ __forceinline__ float bf2f(unsigned short u) {
    union { unsigned int i; float f; } v; v.i = ((unsigned int)u) << 16; return v.f;
}
__device__ __forceinline__ unsigned short f2bf(float f) {
    union { unsigned int i; float f; } v; v.f = f;
    unsigned int b = v.i;
    unsigned int r = (b + 0x7FFFu + ((b >> 16) & 1u)) >> 16;
    return (unsigned short)r;
}
__device__ __forceinline__ float leaky(float x) { return x > 0.f ? x : NEG_SLOPE * x; }

// Edge fetch: which=0 -> src, which=1 -> dst. iflag=1 -> int32, 0 -> int64.
__device__ __forceinline__ int eget(const int* e32, const int* iflag, int which, int e) {
    int idx = which * NEDGES + e;
    return (*iflag) ? e32[idx] : e32[2 * idx];
}

__global__ void zero_int_kernel(int* p, int n) {
    int i = blockIdx.x * 256 + threadIdx.x;
    if (i < n) p[i] = 0;
}
__global__ void zero_f32_kernel(float* p, int n) {
    int i = blockIdx.x * 256 + threadIdx.x;
    if (i < n) p[i] = 0.f;
}

__global__ void detect_f32_kernel(const unsigned short* xb, int* flag) {
    int hit = 0;
    for (int j = threadIdx.x; j < 4096; j += 256) {
        int e = (xb[j] >> 7) & 0xFF;
        if (e >= 0x90) hit = 1;
    }
    if (hit) atomicOr(flag, 1);
}
__global__ void detect_i64_kernel(const int* e32, int* flag) {
    int i = blockIdx.x * 256 + threadIdx.x;
    if (i < NEDGES) {
        if (e32[2 * i + 1] != 0) atomicOr(flag, 1);
    }
}

__global__ void cvt_kernel(const void* src, float* dst, int n, const int* f32flag) {
    int i = blockIdx.x * 256 + threadIdx.x;
    if (i < n)
        dst[i] = (*f32flag) ? ((const float*)src)[i]
                            : bf2f(((const unsigned short*)src)[i]);
}
__global__ void cvt_layerW_kernel(const void* gat_W, float* dst, int l,
                                  const int* f32flag) {
    int i = blockIdx.x * 256 + threadIdx.x;
    if (i < HDIM * HDIM) {
        size_t idx = (size_t)l * HDIM * HDIM + i;
        dst[i] = (*f32flag) ? ((const float*)gat_W)[idx]
                            : bf2f(((const unsigned short*)gat_W)[idx]);
    }
}

// C[M,N] = op(A[M,128] @ B[128,N] + bias). out_f32: C is float*, else bf16 u16*.
__global__ void gemm_any_kernel(const void* Av, int a_dyn, const void* Bv,
                                int b_pre_f32, const float* bias,
                                void* Cv, int out_f32,
                                int M, int N, int relu, const int* f32flag) {
    const int f32 = *f32flag;
    const int a_f32 = a_dyn ? f32 : 0;
    const int b_f32 = b_pre_f32 ? 1 : f32;
    __shared__ float sA[4 * 128];
    const int tid = threadIdx.x;
    const int rpb = 256 / N;
    const int row0 = blockIdx.x * rpb;

    for (int i = tid; i < rpb * 128; i += 256) {
        int r = i >> 7, k = i & 127;
        int gr = row0 + r;
        float v = 0.f;
        if (gr < M) {
            if (a_f32) v = ((const float*)Av)[(size_t)gr * 128 + k];
            else       v = bf2f(((const unsigned short*)Av)[(size_t)gr * 128 + k]);
        }
        sA[i] = v;
    }
    __syncthreads();

    const int r = tid / N, col = tid % N;
    const int row = row0 + r;
    if (row < M) {
        float acc = bias ? bias[col] : 0.f;
        const float* a = &sA[r * 128];
        if (b_f32) {
            const float* B = (const float*)Bv;
            for (int k = 0; k < 128; k++) acc += a[k] * B[(size_t)k * N + col];
        } else {
            const unsigned short* B = (const unsigned short*)Bv;
            for (int k = 0; k < 128; k++) acc += a[k] * bf2f(B[(size_t)k * N + col]);
        }
        if (relu) acc = fmaxf(acc, 0.f);
        if (out_f32) ((float*)Cv)[(size_t)row * N + col] = acc;
        else         ((unsigned short*)Cv)[(size_t)row * N + col] = f2bf(acc);
    }
}

__global__ void alpha_kernel(const unsigned short* xw,
                             const float* a_s, const float* a_d,
                             float* alpha_s, float* alpha_d) {
    int wave = threadIdx.x >> 6, lane = threadIdx.x & 63;
    int n = blockIdx.x * 4 + wave;
    if (n >= NNODES) return;
    float v0 = bf2f(xw[(size_t)n * HDIM + lane]);
    float v1 = bf2f(xw[(size_t)n * HDIM + 64 + lane]);
    float ds = v0 * a_s[lane] + v1 * a_s[64 + lane];
    float dd = v0 * a_d[lane] + v1 * a_d[64 + lane];
    for (int d = 32; d >= 1; d >>= 1) { ds += __shfl_xor(ds, d); dd += __shfl_xor(dd, d); }
    if (lane == 0) { alpha_s[n] = ds; alpha_d[n] = dd; }
}

// ---- CSR build (group edges by dst); proven equivalent to atomics (r9==r10) ----
__global__ void count_kernel(const int* e32, const int* iflag, int* cnt) {
    int e = blockIdx.x * 256 + threadIdx.x;
    if (e < NEDGES) atomicAdd(&cnt[eget(e32, iflag, 1, e)], 1);
}
__global__ void scan1_kernel(const int* cnt, int* off, int* bsum) {
    __shared__ int s[256];
    int t = threadIdx.x, i = blockIdx.x * 256 + t;
    int v = (i < NNODES) ? cnt[i] : 0;
    s[t] = v;
    __syncthreads();
    for (int d = 1; d < 256; d <<= 1) {
        int add = (t >= d) ? s[t - d] : 0;
        __syncthreads();
        s[t] += add;
        __syncthreads();
    }
    if (i < NNODES) off[i] = s[t] - v;          // exclusive
    if (t == 255) bsum[blockIdx.x] = s[255];
}
__global__ void scan2_kernel(int* bsum, int nblk) {
    if (threadIdx.x == 0 && blockIdx.x == 0) {
        int run = 0;
        for (int c = 0; c < nblk; c++) { int t = bsum[c]; bsum[c] = run; run += t; }
    }
}
__global__ void scan3_kernel(int* off, const int* bsum) {
    int i = blockIdx.x * 256 + threadIdx.x;
    if (i < NNODES) off[i] += bsum[blockIdx.x];
}
__global__ void fill_kernel(const int* e32, const int* iflag, const int* off,
                            int* cur, int* csr_src) {
    int e = blockIdx.x * 256 + threadIdx.x;
    if (e < NEDGES) {
        int d = eget(e32, iflag, 1, e);
        int p = atomicAdd(&cur[d], 1);
        csr_src[off[d] + p] = eget(e32, iflag, 0, e);
    }
}

// GAT aggregation (gather): one wave per node; h = relu(h + agg + b) in place.
// Self-loop handled analytically (not in CSR).
__global__ void aggregate_kernel(const unsigned short* __restrict__ xw,
                                 const float* __restrict__ as_, const float* __restrict__ ad_,
                                 const int* __restrict__ off, const int* __restrict__ csr_src,
                                 const float* __restrict__ gat_b, unsigned short* __restrict__ h) {
    int wave = threadIdx.x >> 6, lane = threadIdx.x & 63;
    int n = blockIdx.x * 4 + wave;
    if (n >= NNODES) return;
    int o0 = off[n];
    int o1 = (n == NNODES - 1) ? NEDGES : off[n + 1];
    int deg = o1 - o0;
    float adn = ad_[n];
    float lself = leaky(as_[n] + adn);

    float m = lself;
    for (int i = lane; i < deg; i += 64) {
        int s = csr_src[o0 + i];
        m = fmaxf(m, leaky(as_[s] + adn));
    }
    for (int d = 32; d >= 1; d >>= 1) m = fmaxf(m, __shfl_xor(m, d));

    float denom = 0.f, a0 = 0.f, a1 = 0.f;
    for (int i = 0; i < deg; i++) {
        int s = csr_src[o0 + i];
        float p = __expf(leaky(as_[s] + adn) - m);
        denom += p;
        a0 += p * bf2f(xw[(size_t)s * HDIM + lane]);
        a1 += p * bf2f(xw[(size_t)s * HDIM + 64 + lane]);
    }
    float ps = __expf(lself - m);
    denom += ps;
    a0 += ps * bf2f(xw[(size_t)n * HDIM + lane]);
    a1 += ps * bf2f(xw[(size_t)n * HDIM + 64 + lane]);

    float inv = 1.f / denom;
    size_t base = (size_t)n * HDIM;
    float h0 = bf2f(h[base + lane]), h1 = bf2f(h[base + 64 + lane]);
    float b0 = gat_b[lane],          b1 = gat_b[64 + lane];
    h[base + lane]      = f2bf(fmaxf(h0 + a0 * inv + b0, 0.f));
    h[base + 64 + lane] = f2bf(fmaxf(h1 + a1 * inv + b1, 0.f));
}

// ---------------------------------------------------------------------------
// MFMA Edge MLP (validated round 12)
// ---------------------------------------------------------------------------
__global__ __launch_bounds__(256) void edge_mlp_mfma_kernel(
    const unsigned short* __restrict__ h,
    const int* __restrict__ e32, const int* __restrict__ iflag,
    const float* __restrict__ We1, const float* __restrict__ be1,
    const float* __restrict__ We2, const float* __restrict__ be2,
    float* __restrict__ eout)
{
    constexpr int KP = 256 + 8;
    __shared__ unsigned short lEF[64 * KP];       // 33,792 B
    __shared__ float part[64][4][3];              //  3,072 B

    const int tid  = threadIdx.x;
    const int wave = tid >> 6, lane = tid & 63;
    const int quad = lane >> 4, l15 = lane & 15;
    const int ncol0 = wave * 32;

    short8 bw[8][2];
    for (int kk = 0; kk < 8; kk++) {
        for (int nt = 0; nt < 2; nt++) {
            short8 t;
            int n = ncol0 + nt * 16 + l15;
            #pragma unroll
            for (int j = 0; j < 8; j++)
                t[j] = (short)f2bf(We1[(size_t)(kk * 32 + quad * 8 + j) * HDIM + n]);
            bw[kk][nt] = t;
        }
    }

    float w2[2][3], b1v[2];
    for (int nt = 0; nt < 2; nt++) {
        int n = ncol0 + nt * 16 + l15;
        b1v[nt] = be1[n];
        for (int c = 0; c < 3; c++) w2[nt][c] = We2[n * 3 + c];
    }
    float be2v[3];
    for (int c = 0; c < 3; c++) be2v[c] = be2[c];

    f32x4 vzero; vzero[0] = 0.f; vzero[1] = 0.f; vzero[2] = 0.f; vzero[3] = 0.f;

    const int ntiles = NEDGES / 64;               // 12500
    for (int tile = blockIdx.x; tile < ntiles; tile += gridDim.x) {
        const int e0 = tile * 64;
        for (int c = tid; c < 64 * 32; c += 256) {
            int r = c >> 5, ck = c & 31;
            int e = e0 + r;
            int node = eget(e32, iflag, (ck < 16) ? 0 : 1, e);
            uint4 v = *(const uint4*)(h + (size_t)node * HDIM + (ck & 15) * 8);
            *(uint4*)(&lEF[r * KP + ck * 8]) = v;
        }
        __syncthreads();

        f32x4 acc[4][2];
        for (int mt = 0; mt < 4; mt++)
            for (int nt = 0; nt < 2; nt++)
                acc[mt][nt] = vzero;

        #pragma unroll
        for (int kk = 0; kk < 8; kk++) {
            short8 a[4];
            #pragma unroll
            for (int mt = 0; mt < 4; mt++)
                a[mt] = *(const short8*)(&lEF[(mt * 16 + l15) * KP + kk * 32 + quad * 8]);
            #pragma unroll
            for (int mt = 0; mt < 4; mt++)
                #pragma unroll
                for (int nt = 0; nt < 2; nt++)
                    acc[mt][nt] = __builtin_amdgcn_mfma_f32_16x16x32_bf16(a[mt], bw[kk][nt], acc[mt][nt], 0, 0, 0);
        }

        #pragma unroll
        for (int mt = 0; mt < 4; mt++) {
            #pragma unroll
            for (int q = 0; q < 4; q++) {
                int r = mt * 16 + quad * 4 + q;
                float s0 = 0.f, s1 = 0.f, s2 = 0.f;
                #pragma unroll
                for (int nt = 0; nt < 2; nt++) {
                    float v = fmaxf(acc[mt][nt][q] + b1v[nt], 0.f);
                    s0 += v * w2[nt][0]; s1 += v * w2[nt][1]; s2 += v * w2[nt][2];
                }
                #pragma unroll
                for (int d = 1; d < 16; d <<= 1) {
                    s0 += __shfl_xor(s0, d); s1 += __shfl_xor(s1, d); s2 += __shfl_xor(s2, d);
                }
                if (l15 == 0) { part[r][wave][0] = s0; part[r][wave][1] = s1; part[r][wave][2] = s2; }
            }
        }
        __syncthreads();

        for (int idx = tid; idx < 64 * 3; idx += 256) {
            int e = idx / 3, c = idx % 3;
            eout[(size_t)(e0 + e) * 3 + c] =
                part[e][0][c] + part[e][1][c] + part[e][2][c] + part[e][3][c] + be2v[c];
        }
        __syncthreads();
    }
}

__global__ void gsum_kernel(const unsigned short* h, float* gsum) {
    int f = threadIdx.x;
    float local = 0.f;
    int n0 = blockIdx.x * 200;
    for (int j = 0; j < 200; j++) local += bf2f(h[(size_t)(n0 + j) * HDIM + f]);
    atomicAdd(&gsum[f], local);
}
__global__ void gout_kernel(const float* gsum, float* out) {
    int f = threadIdx.x;
    out[GEMB_OFF + f] = gsum[f] * (1.f / (float)NNODES);
}

extern "C" __attribute__((visibility("default")))
void kernel_launch(void* const* d_in, const int* in_sizes, int n_in,
                   void* d_out, int out_size, void* d_ws, size_t ws_size,
                   hipStream_t stream) {
    const void* x      = d_in[0];
    const int*  eidx   = (const int*)d_in[1];
    const void* W_emb  = d_in[2];
    const void* b_emb  = d_in[3];
    const void* gat_W  = d_in[4];
    const void* gat_as = d_in[5];
    const void* gat_ad = d_in[6];
    const void* gat_b  = d_in[7];
    const void* Wn1    = d_in[8];
    const void* bn1    = d_in[9];
    const void* Wn2    = d_in[10];
    const void* bn2    = d_in[11];
    const void* We1    = d_in[12];
    const void* be1    = d_in[13];
    const void* We2    = d_in[14];
    const void* be2    = d_in[15];
    float* out = (float*)d_out;   // output dtype: float32 (confirmed round 11)

    char* ws = (char*)d_ws;
    unsigned short* h       = (unsigned short*)(ws);                // 12.8 MB
    unsigned short* xw      = (unsigned short*)(ws + 12800000);     // 12.8 MB
    float*          alpha_s = (float*)(ws + 25600000);              // 200 KB
    float*          alpha_d = (float*)(ws + 25800000);              // 200 KB
    int*            cnt     = (int*)(ws + 26000000);                // 200 KB
    int*            off     = (int*)(ws + 26200000);                // 200 KB
    int*            bsum    = (int*)(ws + 26400000);                // 1 KB
    float*          gsum    = (float*)(ws + 26401024);              // 512 B
    int*            iflag   = (int*)(ws + 26401536);
    int*            fflag   = (int*)(ws + 26401540);
    float*          We1c    = (float*)(ws + 26402048);              // 128 KB
    float*          We2c    = (float*)(ws + 26533120);
    float*          asc     = (float*)(ws + 26534656);
    float*          adc     = (float*)(ws + 26536192);
    float*          gbc     = (float*)(ws + 26537728);
    float*          bembc   = (float*)(ws + 26539264);
    float*          bn1c    = (float*)(ws + 26539776);
    float*          bn2c    = (float*)(ws + 26540288);
    float*          be1c    = (float*)(ws + 26540544);
    float*          be2c    = (float*)(ws + 26541056);
    float*          Wlc     = (float*)(ws + 26542080);              // 64 KB
    int*            csr_src = (int*)(ws + 26608000);                // 3.2 MB -> ~29.8 MB top

    const int node_blks = (NNODES + 255) / 256;    // 196
    const int edge_blks = (NEDGES + 255) / 256;    // 3125

    zero_int_kernel<<<1, 256, 0, stream>>>(iflag, 2);
    zero_int_kernel<<<node_blks, 256, 0, stream>>>(cnt, NNODES);
    zero_f32_kernel<<<1, 256, 0, stream>>>(gsum, HDIM);

    detect_f32_kernel<<<1, 256, 0, stream>>>((const unsigned short*)x, fflag);
    detect_i64_kernel<<<edge_blks, 256, 0, stream>>>(eidx, iflag);

    cvt_kernel<<<128, 256, 0, stream>>>(We1, We1c, 256 * 128, fflag);
    cvt_kernel<<<2, 256, 0, stream>>>(We2, We2c, 128 * 3, fflag);
    cvt_kernel<<<2, 256, 0, stream>>>(gat_as, asc, 3 * 128, fflag);
    cvt_kernel<<<2, 256, 0, stream>>>(gat_ad, adc, 3 * 128, fflag);
    cvt_kernel<<<2, 256, 0, stream>>>(gat_b, gbc, 3 * 128, fflag);
    cvt_kernel<<<1, 256, 0, stream>>>(b_emb, bembc, 128, fflag);
    cvt_kernel<<<1, 256, 0, stream>>>(bn1, bn1c, 128, fflag);
    cvt_kernel<<<1, 256, 0, stream>>>(bn2, bn2c, 64, fflag);
    cvt_kernel<<<1, 256, 0, stream>>>(be1, be1c, 128, fflag);
    cvt_kernel<<<1, 256, 0, stream>>>(be2, be2c, 3, fflag);

    // h = relu(x @ W_emb + b_emb)
    gemm_any_kernel<<<(NNODES + 1) / 2, 256, 0, stream>>>(
        x, 1, W_emb, 0, bembc, h, 0, NNODES, 128, 1, fflag);

    // CSR build (once)
    count_kernel<<<edge_blks, 256, 0, stream>>>(eidx, iflag, cnt);
    scan1_kernel<<<node_blks, 256, 0, stream>>>(cnt, off, bsum);
    scan2_kernel<<<1, 64, 0, stream>>>(bsum, node_blks);
    scan3_kernel<<<node_blks, 256, 0, stream>>>(off, bsum);
    zero_int_kernel<<<node_blks, 256, 0, stream>>>(cnt, NNODES);
    fill_kernel<<<edge_blks, 256, 0, stream>>>(eidx, iflag, off, cnt, csr_src);

    for (int l = 0; l < NLAYERS; l++) {
        cvt_layerW_kernel<<<64, 256, 0, stream>>>(gat_W, Wlc, l, fflag);
        gemm_any_kernel<<<(NNODES + 1) / 2, 256, 0, stream>>>(
            h, 0, Wlc, 1, (const float*)0, xw, 0, NNODES, 128, 0, fflag);
        alpha_kernel<<<(NNODES + 3) / 4, 256, 0, stream>>>(
            xw, asc + l * HDIM, adc + l * HDIM, alpha_s, alpha_d);
        aggregate_kernel<<<(NNODES + 3) / 4, 256, 0, stream>>>(
            xw, alpha_s, alpha_d, off, csr_src, gbc + l * HDIM, h);
    }

    // node MLP
    gemm_any_kernel<<<(NNODES + 1) / 2, 256, 0, stream>>>(
        h, 0, Wn1, 0, bn1c, xw, 0, NNODES, 128, 1, fflag);
    gemm_any_kernel<<<(NNODES + 3) / 4, 256, 0, stream>>>(
        xw, 0, Wn2, 0, bn2c, out, 1, NNODES, 64, 0, fflag);

    // edge MLP (MFMA)
    edge_mlp_mfma_kernel<<<12500, 256, 0, stream>>>(
        h, eidx, iflag, We1c, be1c, We2c, be2c, out + NODE_OUT_ELEMS);

    // graph embedding
    gsum_kernel<<<NNODES / 200, 128, 0, stream>>>(h, gsum);
    gout_kernel<<<1, 128, 0, stream>>>(gsum, out);
}